// Round 11
// baseline (433.911 us; speedup 1.0000x reference)
//
#include <hip/hip_runtime.h>
#include <hip/hip_bf16.h>
#include <cstdint>

// Problem constants: B=2, S=2048, D=2048, H=16, DH=128, past_length=0 (fixed).

typedef __attribute__((ext_vector_type(8))) __bf16 bf16x8;
typedef __attribute__((ext_vector_type(4))) float f32x4;
typedef __attribute__((ext_vector_type(16))) float f32x16;
typedef __attribute__((ext_vector_type(4))) float floatv4;
typedef __attribute__((ext_vector_type(4))) unsigned short ushortv4;
typedef __attribute__((ext_vector_type(4))) unsigned int uintv4;

__device__ __forceinline__ unsigned short f2bf(float f) {
    union { float f; unsigned u; } v; v.f = f;
    unsigned r = v.u + 0x7fffu + ((v.u >> 16) & 1u);
    return (unsigned short)(r >> 16);
}

__device__ __forceinline__ unsigned pk2(float a, float b) {
    return (unsigned)f2bf(a) | ((unsigned)f2bf(b) << 16);
}

__device__ __forceinline__ f32x16 zero16() {
    f32x16 z;
#pragma unroll
    for (int i = 0; i < 16; ++i) z[i] = 0.f;
    return z;
}

// global -> LDS async copy, 16B per lane. LDS dest = wave-uniform base + lane*16;
// global source is per-lane (enables swizzled staging via pre-swizzled source).
#define GLL16(g, l)                                                                   \
    __builtin_amdgcn_global_load_lds(                                                 \
        (const __attribute__((address_space(1))) void*)(uintptr_t)(g),                \
        (__attribute__((address_space(3))) void*)(unsigned)(uintptr_t)(l), 16, 0, 0)

// ---------------- cast kernels ----------------
__global__ __launch_bounds__(256) void cast_bf16_k(const float* __restrict__ src,
                                                   unsigned short* __restrict__ dst, int n4) {
    int i = blockIdx.x * 256 + threadIdx.x;
    if (i >= n4) return;
    floatv4 v = reinterpret_cast<const floatv4*>(src)[i];
    ushortv4 o;
    o.x = f2bf(v.x); o.y = f2bf(v.y); o.z = f2bf(v.z); o.w = f2bf(v.w);
    reinterpret_cast<ushortv4*>(dst)[i] = o;
}

// wkv (2048 x 256) f32 -> wkvT (256 x 2048) bf16
__global__ __launch_bounds__(256) void cast_t_wkv_k(const float* __restrict__ src,
                                                    unsigned short* __restrict__ dst) {
    int i = blockIdx.x * 256 + threadIdx.x;  // 0..524287
    int k = i >> 8, j = i & 255;
    dst[j * 2048 + k] = f2bf(src[i]);
}

// ---------------- BT GEMM, K-split: C[M][N] += A[M][K_z] * B[N][K_z]^T ------------
// CHANGE vs round 9: blockIdx.z splits the K range (gridDim.z chunks); epilogue is
// unsafeAtomicAdd into a pre-zeroed C. Doubles/quadruples blocks/CU (2 -> 3-4) to
// hide the stage->barrier drain with more wave-level overlap (m97 regime).
__global__ __launch_bounds__(256) void gemm_bt(const unsigned short* __restrict__ A,
                                               const unsigned short* __restrict__ B,
                                               float* __restrict__ C,
                                               int M, int N, int K) {
    __shared__ __align__(16) unsigned short As[4096];  // [128][32]
    __shared__ __align__(16) unsigned short Bs[4096];
    const int tid  = threadIdx.x;
    const int lane = tid & 63;
    const int wid  = tid >> 6;
    const int wr   = wid >> 1;
    const int wc   = wid & 1;
    const size_t row0 = (size_t)blockIdx.y * 128;
    const size_t col0 = (size_t)blockIdx.x * 128;
    const int Kc = K / gridDim.z;            // multiple of 32 by construction
    const int kbeg = blockIdx.z * Kc;
    const int kend = kbeg + Kc;
    f32x4 acc[4][4];
#pragma unroll
    for (int m = 0; m < 4; ++m)
#pragma unroll
        for (int n = 0; n < 4; ++n) acc[m][n] = (f32x4){0.f, 0.f, 0.f, 0.f};

    const int srow = tid >> 2;
    const int scol = (tid & 3) << 3;
    const unsigned short* Ag = A + (row0 + srow) * (size_t)K + scol;
    const unsigned short* Bg = B + (col0 + srow) * (size_t)K + scol;
    unsigned short* AsW = &As[wid << 9];
    unsigned short* BsW = &Bs[wid << 9];

    const int lrow = lane & 15;
    const int lk   = (lane >> 4) << 3;

    for (int k0 = kbeg; k0 < kend; k0 += 32) {
        GLL16(Ag + k0, AsW);
        GLL16(Ag + k0 + (size_t)64 * K, AsW + 2048);
        GLL16(Bg + k0, BsW);
        GLL16(Bg + k0 + (size_t)64 * K, BsW + 2048);
        __syncthreads();
        bf16x8 af[4], bfr[4];
#pragma unroll
        for (int m = 0; m < 4; ++m)
            af[m] = *reinterpret_cast<const bf16x8*>(&As[(wr * 64 + m * 16 + lrow) * 32 + lk]);
#pragma unroll
        for (int n = 0; n < 4; ++n)
            bfr[n] = *reinterpret_cast<const bf16x8*>(&Bs[(wc * 64 + n * 16 + lrow) * 32 + lk]);
#pragma unroll
        for (int m = 0; m < 4; ++m)
#pragma unroll
            for (int n = 0; n < 4; ++n)
                acc[m][n] = __builtin_amdgcn_mfma_f32_16x16x32_bf16(af[m], bfr[n], acc[m][n], 0, 0, 0);
        __syncthreads();
    }
    const size_t orow0 = row0 + wr * 64 + ((lane >> 4) << 2);
    const size_t ocol  = col0 + wc * 64 + lrow;
#pragma unroll
    for (int m = 0; m < 4; ++m)
#pragma unroll
        for (int n = 0; n < 4; ++n)
#pragma unroll
            for (int r = 0; r < 4; ++r)
                unsafeAtomicAdd(&C[(orow0 + m * 16 + r) * (size_t)N + ocol + n * 16],
                                acc[m][n][r]);
}

// ---------------- RoPE + pack (unchanged, passed rounds 4/5/7/9) ----------------
__global__ __launch_bounds__(256) void rope_pack_k(const float* __restrict__ Qf,
                                                   const float* __restrict__ KVf,
                                                   unsigned short* __restrict__ Qb,
                                                   unsigned short* __restrict__ Kb,
                                                   unsigned short* __restrict__ Vt,
                                                   float* __restrict__ Kout,
                                                   float* __restrict__ Vout) {
    const int row = blockIdx.x;      // b*2048 + s
    const int b = row >> 11;
    const int s = row & 2047;
    const int t = threadIdx.x;
    const float* qrow = Qf + (size_t)row * 2048;
#pragma unroll
    for (int it = 0; it < 4; ++it) {
        int p = t + it * 256;        // pair index 0..1023
        int h = p >> 6;
        int i = p & 63;
        float fr  = exp2f(-(float)i * 0.20762050593045858f);  // 10000^(-i/64)
        float ang = (float)s * fr;
        float sn, c;
        sincosf(ang, &sn, &c);
        float x1 = qrow[h * 128 + i];
        float x2 = qrow[h * 128 + i + 64];
        size_t qb = (((size_t)(b * 16 + h)) * 2048 + s) * 128;
        Qb[qb + i]      = f2bf(x1 * c - x2 * sn);
        Qb[qb + i + 64] = f2bf(x2 * c + x1 * sn);
    }
    const float* kvrow = KVf + (size_t)row * 256;
    if (t < 128) {
        float kv = kvrow[t];
        float vv = kvrow[128 + t];
        Kout[(size_t)row * 128 + t] = kv;
        Vout[(size_t)row * 128 + t] = vv;
        Vt[((size_t)(b * 128 + t)) * 2048 + s] = f2bf(vv);
    }
    if (t < 64) {
        float fr  = exp2f(-(float)t * 0.20762050593045858f);
        float ang = (float)s * fr;
        float sn, c;
        sincosf(ang, &sn, &c);
        float x1 = kvrow[t];
        float x2 = kvrow[t + 64];
        size_t ko = ((size_t)b * 2048 + s) * 128;
        Kb[ko + t]      = f2bf(x1 * c - x2 * sn);
        Kb[ko + t + 64] = f2bf(x2 * c + x1 * sn);
    }
}

// ---------------- causal flash attention (MQA), LDS staging + 2-phase prefetch ---
// CHANGE vs round 9 (1 line): work balance across co-resident block pairs.
// z=0 blocks take g=15-x (long first), z=1 blocks take g=x, so likely co-resident
// pairs (i, i+256) have NKT sums = 34 constant, cutting the worst-CU tail 64->34.
__global__ __launch_bounds__(256, 2) void attn_k(const unsigned short* __restrict__ Qb,
                                                 const unsigned short* __restrict__ Kb,
                                                 const unsigned short* __restrict__ Vt,
                                                 unsigned short* __restrict__ Ob) {
    const int g = blockIdx.z ? blockIdx.x : (15 - blockIdx.x);  // complementary pairs
    const int h = blockIdx.y, b = blockIdx.z;
    const int lane = threadIdx.x & 63;
    const int w = threadIdx.x >> 6;
    const int j = 4 * g + w;                 // this wave's q-tile (0..63)
    const int q0 = j * 32;
    const int lq = lane & 31;                // q row owned by this lane
    const int hl = lane >> 5;                // lane half
    const int kofs = hl * 8;                 // k-dim offset inside a 16-chunk
    const int my_nkt = 2 * g + 1 + (w >> 1); // key tiles for this wave's q-tile
    const int NKT = 2 * g + 2;               // block loop count

    __shared__ __align__(16) unsigned short Ks[2][8192];   // 32 KB (double-buffered)
    __shared__ __align__(16) unsigned short Vs[2][8192];   // 32 KB

    const unsigned short* kbB = Kb + (size_t)b * 2048 * 128;
    const unsigned short* vtB = Vt + (size_t)b * 128 * 2048;
    const float csc = 0.12751782377892224f;  // (1/sqrt(128)) * log2(e)

    // --- staging invariants: wave w covers dest granules [w*256 + c*64 + lane] ---
    int k_r[4], k_gc[4], v_d[4], v_kg[4];
#pragma unroll
    for (int c = 0; c < 4; ++c) {
        int G = w * 256 + c * 64 + lane;
        int r = G >> 4;
        int gc = (G & 15) ^ (r & 15);        // logical granule (self-inverse XOR)
        k_r[c] = r; k_gc[c] = gc;
        v_d[c] = r * 2 + (gc >> 3); v_kg[c] = gc & 7;
    }
    const int dstoff = w * 2048;             // wave dest base (elems) within a buffer

    // --- Q fragment (held in regs) ---
    const unsigned short* qp = Qb + (((size_t)(b * 16 + h)) * 2048 + q0 + lq) * 128 + kofs;
    bf16x8 qf[8];
#pragma unroll
    for (int c = 0; c < 8; ++c)
        qf[c] = *reinterpret_cast<const bf16x8*>(qp + 16 * c);

    f32x16 O[4];
#pragma unroll
    for (int dt = 0; dt < 4; ++dt) O[dt] = zero16();
    float m = -1e30f, l = 0.f;

    // --- prologue: stage tile 0 into buffer 0 ---
#pragma unroll
    for (int c = 0; c < 4; ++c) {
        GLL16(kbB + (size_t)k_r[c] * 128 + k_gc[c] * 8, &Ks[0][dstoff + c * 512]);
        GLL16(vtB + (size_t)v_d[c] * 2048 + v_kg[c] * 8, &Vs[0][dstoff + c * 512]);
    }
    __syncthreads();   // tile 0 ready

    int cur = 0;
    for (int kt = 0; kt < NKT; ++kt) {
        // --- prefetch tile kt+1 into the other buffer (async, no wait) ---
        if (kt + 1 < NKT) {
            const int nxt = cur ^ 1;
#pragma unroll
            for (int c = 0; c < 4; ++c) {
                GLL16(kbB + (size_t)(64 * (kt + 1) + k_r[c]) * 128 + k_gc[c] * 8,
                      &Ks[nxt][dstoff + c * 512]);
                GLL16(vtB + (size_t)v_d[c] * 2048 + (kt + 1) * 64 + v_kg[c] * 8,
                      &Vs[nxt][dstoff + c * 512]);
            }
        }
        if (kt < my_nkt) {
            // --- K fragments from LDS (swizzled read) ---
            bf16x8 kf0[8], kf1[8];
            const int r0 = lq, r1 = lq + 32;
#pragma unroll
            for (int c = 0; c < 8; ++c) {
                kf0[c] = *reinterpret_cast<const bf16x8*>(
                    (const char*)&Ks[cur][0] + r0 * 256 + (((2 * c + hl) ^ (r0 & 15)) * 16));
                kf1[c] = *reinterpret_cast<const bf16x8*>(
                    (const char*)&Ks[cur][0] + r1 * 256 + (((2 * c + hl) ^ (r1 & 15)) * 16));
            }
            // --- S^T = K · Q^T ---
            f32x16 S0 = zero16(), S1 = zero16();
#pragma unroll
            for (int c = 0; c < 8; ++c) {
                S0 = __builtin_amdgcn_mfma_f32_32x32x16_bf16(kf0[c], qf[c], S0, 0, 0, 0);
                S1 = __builtin_amdgcn_mfma_f32_32x32x16_bf16(kf1[c], qf[c], S1, 0, 0, 0);
            }
            // --- softmax (verbatim) ---
            float sc[32];
            const bool lastt = (kt == my_nkt - 1);
#pragma unroll
            for (int s = 0; s < 2; ++s)
#pragma unroll
                for (int r = 0; r < 16; ++r) {
                    float v = (s ? S1[r] : S0[r]) * csc;
                    if (lastt) {
                        int key = 64 * kt + 32 * s + (r & 3) + 8 * (r >> 2) + 4 * hl;
                        if (key > q0 + lq) v = -3.0e38f;
                    }
                    sc[16 * s + r] = v;
                }
            float tm[16];
#pragma unroll
            for (int i = 0; i < 16; ++i) tm[i] = fmaxf(sc[i], sc[i + 16]);
#pragma unroll
            for (int st = 8; st > 0; st >>= 1)
#pragma unroll
                for (int i = 0; i < st; ++i) tm[i] = fmaxf(tm[i], tm[i + st]);
            float mt = fmaxf(tm[0], __shfl_xor(tm[0], 32));
            float mn = fmaxf(m, mt);
            float corr = __builtin_amdgcn_exp2f(m - mn);
            m = mn;
#pragma unroll
            for (int i = 0; i < 32; ++i) sc[i] = __builtin_amdgcn_exp2f(sc[i] - mn);
            float ts[16];
#pragma unroll
            for (int i = 0; i < 16; ++i) ts[i] = sc[i] + sc[i + 16];
#pragma unroll
            for (int st = 8; st > 0; st >>= 1)
#pragma unroll
                for (int i = 0; i < st; ++i) ts[i] += ts[i + st];
            l = l * corr + ts[0] + __shfl_xor(ts[0], 32);
#pragma unroll
            for (int dt = 0; dt < 4; ++dt)
#pragma unroll
                for (int r = 0; r < 16; ++r) O[dt][r] *= corr;
            // --- pack P into PV B-fragments (verbatim) ---
            unsigned pw[4][4];
#pragma unroll
            for (int s = 0; s < 2; ++s)
#pragma unroll
                for (int c2 = 0; c2 < 2; ++c2) {
                    const int rb = 16 * s + 8 * c2;
                    unsigned X0 = pk2(sc[rb + 0], sc[rb + 1]);
                    unsigned X1 = pk2(sc[rb + 2], sc[rb + 3]);
                    unsigned X2 = pk2(sc[rb + 4], sc[rb + 5]);
                    unsigned X3 = pk2(sc[rb + 6], sc[rb + 7]);
                    unsigned y0 = __shfl_xor(X0, 32);
                    unsigned y1 = __shfl_xor(X1, 32);
                    unsigned y2 = __shfl_xor(X2, 32);
                    unsigned y3 = __shfl_xor(X3, 32);
                    const int kc = 2 * s + c2;
                    pw[kc][0] = hl ? y2 : X0;
                    pw[kc][1] = hl ? y3 : X1;
                    pw[kc][2] = hl ? X2 : y0;
                    pw[kc][3] = hl ? X3 : y1;
                }
            // --- O^T += V^T · P^T, V fragments from LDS (swizzled read) ---
            const int vrow_lo = lq >> 1;     // (row & 15)
            const int vpar8 = (lq & 1) * 8;
#pragma unroll
            for (int kc = 0; kc < 4; ++kc) {
                uintv4 u;
                u.x = pw[kc][0]; u.y = pw[kc][1]; u.z = pw[kc][2]; u.w = pw[kc][3];
                bf16x8 pf = __builtin_bit_cast(bf16x8, u);
                const int gcl = vpar8 + 2 * kc + hl;
#pragma unroll
                for (int dt = 0; dt < 4; ++dt) {
                    const int vrow = 16 * dt + vrow_lo;
                    bf16x8 vf = *reinterpret_cast<const bf16x8*>(
                        (const char*)&Vs[cur][0] + vrow * 256 + ((gcl ^ vrow_lo) * 16));
                    O[dt] = __builtin_amdgcn_mfma_f32_32x32x16_bf16(vf, pf, O[dt], 0, 0, 0);
                }
            }
        }
        __syncthreads();   // drains prefetch vmcnt + guards buffer reuse
        cur ^= 1;
    }

    // --- epilogue (verbatim) ---
    float invl = 1.f / l;
    unsigned short* ob = Ob + ((size_t)(b * 2048 + q0 + lq)) * 2048 + h * 128;
#pragma unroll
    for (int dt = 0; dt < 4; ++dt)
#pragma unroll
        for (int gg = 0; gg < 4; ++gg) {
            ushortv4 ov;
            ov.x = f2bf(O[dt][4 * gg + 0] * invl);
            ov.y = f2bf(O[dt][4 * gg + 1] * invl);
            ov.z = f2bf(O[dt][4 * gg + 2] * invl);
            ov.w = f2bf(O[dt][4 * gg + 3] * invl);
            *reinterpret_cast<ushortv4*>(ob + 32 * dt + 8 * gg + 4 * hl) = ov;
        }
}

// ---------------- launch ----------------
extern "C" void kernel_launch(void* const* d_in, const int* in_sizes, int n_in,
                              void* d_out, int out_size, void* d_ws, size_t ws_size,
                              hipStream_t stream) {
    const float* x   = (const float*)d_in[0];
    const float* wq  = (const float*)d_in[1];
    const float* wkv = (const float*)d_in[2];
    const float* wo  = (const float*)d_in[3];

    float* out  = (float*)d_out;                 // (B,S,D) = 8388608
    float* Kout = out + 8388608;                 // (B,S,DH) = 524288
    float* Vout = Kout + 524288;

    char* ws = (char*)d_ws;
    unsigned short* xb   = (unsigned short*)(ws + 0);          // 16 MB
    unsigned short* wqb  = (unsigned short*)(ws + 16777216);   //  8 MB
    unsigned short* wkvT = (unsigned short*)(ws + 25165824);   //  1 MB
    unsigned short* wob  = (unsigned short*)(ws + 26214400);   //  8 MB
    float*          KVf  = (float*)(ws + 34603008);            //  4 MB
    float*          Qf   = (float*)(ws + 38797312);            // 32 MB
    unsigned short* Qb   = (unsigned short*)(ws + 0);          // 16 MB (aliases xb)
    unsigned short* Kb   = (unsigned short*)(ws + 16777216);   //  1 MB (aliases wqb)
    unsigned short* Vt   = (unsigned short*)(ws + 17825792);   //  1 MB (aliases wqb)
    unsigned short* Ob   = (unsigned short*)(ws + 34603008);   // 16 MB (aliases KVf/Qf)

    // zero the K-split accumulation targets (atomic-add epilogues)
    hipMemsetAsync(KVf, 0, 4194304, stream);     // 4096 x 256 f32
    hipMemsetAsync(Qf,  0, 33554432, stream);    // 4096 x 2048 f32
    hipMemsetAsync(out, 0, 33554432, stream);    // 4096 x 2048 f32

    cast_bf16_k<<<8192, 256, 0, stream>>>(x,  xb,  2097152);
    cast_bf16_k<<<4096, 256, 0, stream>>>(wq, wqb, 1048576);
    cast_bf16_k<<<4096, 256, 0, stream>>>(wo, wob, 1048576);
    cast_t_wkv_k<<<2048, 256, 0, stream>>>(wkv, wkvT);

    gemm_bt<<<dim3(2, 32, 4),  256, 0, stream>>>(xb, wkvT, KVf, 4096, 256,  2048);
    gemm_bt<<<dim3(16, 32, 2), 256, 0, stream>>>(xb, wqb,  Qf,  4096, 2048, 2048);

    rope_pack_k<<<4096, 256, 0, stream>>>(Qf, KVf, Qb, Kb, Vt, Kout, Vout);

    attn_k<<<dim3(16, 16, 2), 256, 0, stream>>>(Qb, Kb, Vt, Ob);

    gemm_bt<<<dim3(16, 32, 2), 256, 0, stream>>>(Ob, wob, out, 4096, 2048, 2048);
}